// Round 3
// baseline (584.003 us; speedup 1.0000x reference)
//
#include <hip/hip_runtime.h>
#include <hip/hip_bf16.h>

#define NODES 100000
#define EDGES 1600000
#define FEAT 512
#define HID 128
#define NCLS 40
#define NPAD 48                      // NCLS padded to 3 MFMA n-tiles

// ---- bucketed CSR build params ----
#define NPB 128                          // nodes per bucket (dst >> 7)
#define NB_BKT ((NODES + NPB - 1) / NPB) // 782 buckets
#define CAP 4096                         // slots per bucket (expected 2048, sigma 45)
#define CHUNK 4096                       // edges per workgroup in binning
#define NWG_BIN ((EDGES + CHUNK - 1) / CHUNK)  // 391

typedef __bf16 bf16x8 __attribute__((ext_vector_type(8)));
typedef float f32x4 __attribute__((ext_vector_type(4)));

static __device__ inline __bf16 cvt_bf16(float f) {
  union { __hip_bfloat16 h; __bf16 b; } u;
  u.h = __float2bfloat16(f);
  return u.b;
}

static __device__ inline __hip_bfloat162 pack_bf162(float a, float b) {
  __hip_bfloat162 r;
  r.x = __float2bfloat16(a);
  r.y = __float2bfloat16(b);
  return r;
}

// ---------------- CSR build, bucketed, fixed-capacity ----------------
// k1: per-wg LDS histogram + bucket range reservation, packed scatter into
// bucket-strided staging at b*CAP. payload = (src<<7) | (dst & 127)
__global__ __launch_bounds__(256) void bin_scatter(const int* __restrict__ ei,
                                                   int* __restrict__ bcur,
                                                   unsigned int* __restrict__ staged) {
  __shared__ int h[NB_BKT];
  int tid = threadIdx.x;
  for (int i = tid; i < NB_BKT; i += 256) h[i] = 0;
  __syncthreads();
  int base = blockIdx.x * CHUNK;
  // pass A: count this chunk
#pragma unroll
  for (int rep = 0; rep < CHUNK / 1024; rep++) {
    int e = base + rep * 1024 + (tid << 2);
    if (e < EDGES) {  // EDGES % 4 == 0, so full int4 is in-bounds
      int4 d = *(const int4*)(ei + EDGES + e);
      atomicAdd(&h[d.x >> 7], 1);
      atomicAdd(&h[d.y >> 7], 1);
      atomicAdd(&h[d.z >> 7], 1);
      atomicAdd(&h[d.w >> 7], 1);
    }
  }
  __syncthreads();
  // reserve within-bucket ranges; convert h[] into running write cursors
  for (int i = tid; i < NB_BKT; i += 256) {
    int c = h[i];
    h[i] = c ? atomicAdd(&bcur[i], c) : 0;
  }
  __syncthreads();
  // pass B: scatter packed payloads into reserved runs
#pragma unroll
  for (int rep = 0; rep < CHUNK / 1024; rep++) {
    int e = base + rep * 1024 + (tid << 2);
    if (e < EDGES) {
      int4 s = *(const int4*)(ei + e);
      int4 d = *(const int4*)(ei + EDGES + e);
      int b0 = d.x >> 7;
      int p0 = atomicAdd(&h[b0], 1);
      staged[b0 * CAP + p0] = ((unsigned)s.x << 7) | ((unsigned)d.x & 127u);
      int b1 = d.y >> 7;
      int p1 = atomicAdd(&h[b1], 1);
      staged[b1 * CAP + p1] = ((unsigned)s.y << 7) | ((unsigned)d.y & 127u);
      int b2 = d.z >> 7;
      int p2 = atomicAdd(&h[b2], 1);
      staged[b2 * CAP + p2] = ((unsigned)s.z << 7) | ((unsigned)d.z & 127u);
      int b3 = d.w >> 7;
      int p3 = atomicAdd(&h[b3], 1);
      staged[b3 * CAP + p3] = ((unsigned)s.w << 7) | ((unsigned)d.w & 127u);
    }
  }
}

// k2: one wg per bucket: per-node histogram + padded scan (-> deg, dinv,
// row_start 16B-aligned), node-grouped scatter into bucket-strided adj
__global__ __launch_bounds__(256) void build_bucket(const unsigned int* __restrict__ staged,
                                                    const int* __restrict__ bcur,
                                                    int* __restrict__ deg,
                                                    float* __restrict__ dinv,
                                                    int* __restrict__ row_start,
                                                    int* __restrict__ adj) {
  __shared__ int hist[NPB];
  __shared__ int sc[NPB];
  __shared__ int cur[NPB];
  int tid = threadIdx.x;
  int b = blockIdx.x;
  int n0 = b * NPB;
  int s = b * CAP;
  int cnt = bcur[b];
  if (tid < NPB) hist[tid] = 0;
  __syncthreads();
  for (int i = tid; i < cnt; i += 256) {
    unsigned int v = staged[s + i];
    atomicAdd(&hist[v & 127u], 1);
  }
  __syncthreads();
  int pad = 0;
  if (tid < NPB) {
    pad = (hist[tid] + 3) & ~3;  // 16B-aligned rows for int4 adj loads
    sc[tid] = pad;
  }
  __syncthreads();
#pragma unroll
  for (int off = 1; off < NPB; off <<= 1) {
    int t = 0;
    if (tid < NPB && tid >= off) t = sc[tid - off];
    __syncthreads();
    if (tid < NPB && tid >= off) sc[tid] += t;
    __syncthreads();
  }
  if (tid < NPB) {
    int node = n0 + tid;
    int rs = s + sc[tid] - pad;   // sum of pads <= cnt + 3*128 < CAP
    cur[tid] = rs;
    if (node < NODES) {
      row_start[node] = rs;
      deg[node] = hist[tid];
      dinv[node] = rsqrtf((float)hist[tid] + 1.0f);  // +1 = self loop
    }
  }
  __syncthreads();
  for (int i = tid; i < cnt; i += 256) {
    unsigned int v = staged[s + i];
    int pos = atomicAdd(&cur[v & 127u], 1);
    adj[pos] = (int)(v >> 7);
  }
}

// ---------------- weight transposes (f32 -> bf16), merged ----------------
__global__ void tr_w(const float* __restrict__ w1, const float* __restrict__ w2,
                     __hip_bfloat16* __restrict__ w1t, __hip_bfloat16* __restrict__ w2t) {
  int idx = blockIdx.x * blockDim.x + threadIdx.x;
  if (idx < FEAT * HID) {
    int k = idx / HID, n = idx % HID;
    w1t[n * FEAT + k] = __float2bfloat16(w1[idx]);
  } else {
    int j = idx - FEAT * HID;
    if (j < NPAD * HID) {
      int n = j / HID, k = j % HID;
      w2t[n * HID + k] = (n < NCLS) ? __float2bfloat16(w2[k * NCLS + n]) : __float2bfloat16(0.0f);
    }
  }
}

// ---------------- GEMM1 v3: no LDS, no barriers, direct-fragment loads ----------------
// BM=64 (1563 blocks, ~6/CU). A-frags read straight from x (f32, 128 B/row/kstep,
// each line touched once); B-frags from w1t (128 KB, L2-resident). Epilogue scales
// by dinv[row].
__global__ __launch_bounds__(256) void gemm1_kernel(const float* __restrict__ x,
                                                    const __hip_bfloat16* __restrict__ w1t,
                                                    const float* __restrict__ dinv,
                                                    __hip_bfloat16* __restrict__ h0s) {
  int tid = threadIdx.x, wave = tid >> 6, lane = tid & 63;
  int r = lane & 15, quad = lane >> 4;
  int m0 = blockIdx.x * 64 + wave * 16;  // this wave's 16-row m-tile
  int row = m0 + r;
  int rowc = (row < NODES) ? row : (NODES - 1);  // clamp; results discarded at store
  const float* ap = x + (size_t)rowc * FEAT + quad * 8;
  const __hip_bfloat16* bp = w1t + (size_t)r * FEAT + quad * 8;

  f32x4 acc[8];
#pragma unroll
  for (int n = 0; n < 8; n++) acc[n] = (f32x4){0.f, 0.f, 0.f, 0.f};

#pragma unroll 4
  for (int ks = 0; ks < 16; ks++) {
    int ko = ks * 32;
    f32x4 a0 = *(const f32x4*)(ap + ko);
    f32x4 a1 = *(const f32x4*)(ap + ko + 4);
    bf16x8 bf[8];
#pragma unroll
    for (int n = 0; n < 8; n++)
      bf[n] = *(const bf16x8*)(bp + (size_t)n * 16 * FEAT + ko);
    bf16x8 af;
    af[0] = cvt_bf16(a0[0]); af[1] = cvt_bf16(a0[1]);
    af[2] = cvt_bf16(a0[2]); af[3] = cvt_bf16(a0[3]);
    af[4] = cvt_bf16(a1[0]); af[5] = cvt_bf16(a1[1]);
    af[6] = cvt_bf16(a1[2]); af[7] = cvt_bf16(a1[3]);
#pragma unroll
    for (int n = 0; n < 8; n++)
      acc[n] = __builtin_amdgcn_mfma_f32_16x16x32_bf16(af, bf[n], acc[n], 0, 0, 0);
  }

  int mrow = m0 + quad * 4;
  f32x4 dv = *(const f32x4*)(dinv + mrow);  // mrow%4==0; OOB rows read ws slack, unused
#pragma unroll
  for (int n = 0; n < 8; n++)
#pragma unroll
    for (int rr = 0; rr < 4; rr++) {
      int orow = mrow + rr;
      if (orow < NODES)
        h0s[(size_t)orow * HID + n * 16 + r] = __float2bfloat16(acc[n][rr] * dv[rr]);
    }
}

// ---------------- fused agg1 + epilogue1: h = relu(di * sum(h0s) + b1) ----------------
// h0s rows pre-scaled by dinv[src]; 16-wide gather unroll for load-latency ILP.
__global__ __launch_bounds__(256) void agg1_fused(
    const int* __restrict__ row_start, const int* __restrict__ deg,
    const int* __restrict__ adj, const float* __restrict__ dinv,
    const float* __restrict__ b1, const __hip_bfloat16* __restrict__ h0s,
    __hip_bfloat16* __restrict__ h) {
  int wave = threadIdx.x >> 6, lane = threadIdx.x & 63;
  int node = blockIdx.x * 4 + wave;
  if (node >= NODES) return;
  float di = dinv[node];
  float2 f = __bfloat1622float2(((const __hip_bfloat162*)(h0s + (size_t)node * HID))[lane]);
  float ax = f.x, ay = f.y;  // self loop: h0s[node] already carries dinv[node]
  int start = row_start[node], end = start + deg[node];
  int p = start;
  for (; p + 16 <= end; p += 16) {  // row_start is 16B-aligned
    int4 a0 = *(const int4*)(adj + p);
    int4 a1 = *(const int4*)(adj + p + 4);
    int4 a2 = *(const int4*)(adj + p + 8);
    int4 a3 = *(const int4*)(adj + p + 12);
    int s[16] = {a0.x, a0.y, a0.z, a0.w, a1.x, a1.y, a1.z, a1.w,
                 a2.x, a2.y, a2.z, a2.w, a3.x, a3.y, a3.z, a3.w};
    float2 v[16];
#pragma unroll
    for (int j = 0; j < 16; j++)
      v[j] = __bfloat1622float2(((const __hip_bfloat162*)(h0s + (size_t)s[j] * HID))[lane]);
#pragma unroll
    for (int j = 0; j < 16; j++) { ax += v[j].x; ay += v[j].y; }
  }
  if (p + 8 <= end) {
    int4 a0 = *(const int4*)(adj + p);
    int4 a1 = *(const int4*)(adj + p + 4);
    int s[8] = {a0.x, a0.y, a0.z, a0.w, a1.x, a1.y, a1.z, a1.w};
    float2 v[8];
#pragma unroll
    for (int j = 0; j < 8; j++)
      v[j] = __bfloat1622float2(((const __hip_bfloat162*)(h0s + (size_t)s[j] * HID))[lane]);
#pragma unroll
    for (int j = 0; j < 8; j++) { ax += v[j].x; ay += v[j].y; }
    p += 8;
  }
  for (; p < end; ++p) {
    int s = adj[p];
    float2 v = __bfloat1622float2(((const __hip_bfloat162*)(h0s + (size_t)s * HID))[lane]);
    ax += v.x;
    ay += v.y;
  }
  float2 b = ((const float2*)b1)[lane];
  ax = fmaxf(ax * di + b.x, 0.0f);
  ay = fmaxf(ay * di + b.y, 0.0f);
  ((__hip_bfloat162*)(h + (size_t)node * HID))[lane] = pack_bf162(ax, ay);
}

// ---------------- GEMM2: h1s[N,40] = (h[N,128] @ W2) * dinv[row] ----------------
__global__ __launch_bounds__(256) void gemm2_kernel(const __hip_bfloat16* __restrict__ h,
                                                    const __hip_bfloat16* __restrict__ w2t,
                                                    const float* __restrict__ dinv,
                                                    float* __restrict__ h1s) {
  int wave = threadIdx.x >> 6;
  int lane = threadIdx.x & 63;
  int m0 = (blockIdx.x * 4 + wave) * 16;
  if (m0 >= NODES) return;
  int r = lane & 15, quad = lane >> 4;
  const bf16x8* arow = (const bf16x8*)(h + (size_t)(m0 + r) * HID + quad * 8);
  f32x4 acc[3];
#pragma unroll
  for (int n = 0; n < 3; n++) acc[n] = (f32x4){0.f, 0.f, 0.f, 0.f};
#pragma unroll
  for (int k0 = 0; k0 < HID; k0 += 32) {
    bf16x8 a = arow[k0 / 8];
#pragma unroll
    for (int n = 0; n < 3; n++) {
      const bf16x8* brow = (const bf16x8*)(w2t + (size_t)(n * 16 + r) * HID + k0 + quad * 8);
      acc[n] = __builtin_amdgcn_mfma_f32_16x16x32_bf16(a, *brow, acc[n], 0, 0, 0);
    }
  }
  f32x4 dv = *(const f32x4*)(dinv + m0 + quad * 4);
#pragma unroll
  for (int n = 0; n < 3; n++)
#pragma unroll
    for (int rr = 0; rr < 4; rr++) {
      int col = n * 16 + r;
      if (col < NCLS)
        h1s[(size_t)(m0 + quad * 4 + rr) * NCLS + col] = acc[n][rr] * dv[rr];
    }
}

// ---------------- fused agg2 + bias + self loop + log_softmax ----------------
__global__ __launch_bounds__(256) void agg2_fused(
    const int* __restrict__ row_start, const int* __restrict__ deg,
    const int* __restrict__ adj, const float* __restrict__ dinv,
    const float* __restrict__ b2, const float* __restrict__ h1s,
    float* __restrict__ out) {
  int wave = threadIdx.x >> 6, lane = threadIdx.x & 63;
  int node = blockIdx.x * 4 + wave;
  if (node >= NODES) return;
  float di = dinv[node];
  bool act = lane < NCLS;
  float acc = act ? h1s[(size_t)node * NCLS + lane] : 0.0f;  // self loop pre-scaled
  int start = row_start[node], end = start + deg[node];
  int p = start;
  for (; p + 8 <= end; p += 8) {
    int4 a0 = *(const int4*)(adj + p);
    int4 a1 = *(const int4*)(adj + p + 4);
    int s[8] = {a0.x, a0.y, a0.z, a0.w, a1.x, a1.y, a1.z, a1.w};
    if (act) {
      float v[8];
#pragma unroll
      for (int j = 0; j < 8; j++) v[j] = h1s[(size_t)s[j] * NCLS + lane];
#pragma unroll
      for (int j = 0; j < 8; j++) acc += v[j];
    }
  }
  for (; p < end; ++p) {
    int s = adj[p];
    if (act) acc += h1s[(size_t)s * NCLS + lane];
  }
  float v = act ? acc * di + b2[lane] : -1e30f;
  float m = v;
#pragma unroll
  for (int o = 32; o > 0; o >>= 1) m = fmaxf(m, __shfl_xor(m, o));
  float ex = act ? expf(v - m) : 0.0f;
  float ssum = ex;
#pragma unroll
  for (int o = 32; o > 0; o >>= 1) ssum += __shfl_xor(ssum, o);
  if (act) out[(size_t)node * NCLS + lane] = v - m - logf(ssum);
}

extern "C" void kernel_launch(void* const* d_in, const int* in_sizes, int n_in,
                              void* d_out, int out_size, void* d_ws, size_t ws_size,
                              hipStream_t stream) {
  const float* x  = (const float*)d_in[0];
  const int* ei   = (const int*)d_in[1];
  const float* W1 = (const float*)d_in[2];
  const float* b1 = (const float*)d_in[3];
  const float* W2 = (const float*)d_in[4];
  const float* b2 = (const float*)d_in[5];
  float* out = (float*)d_out;

  char* ws = (char*)d_ws;
  int* deg_i          = (int*)(ws + 0);                    // 400 KB
  float* dinv         = (float*)(ws + (size_t)512 * 1024); // 400 KB
  int* row_start      = (int*)(ws + (size_t)1024 * 1024);  // 400 KB
  int* bcur           = (int*)(ws + (size_t)1536 * 1024);  // ~3.1 KB
  int* adj            = (int*)(ws + (size_t)2 * 1048576);  // 12.8 MB -> ends ~14.8 MB
  __hip_bfloat16* w1t = (__hip_bfloat16*)(ws + (size_t)15 * 1048576);  // 128 KB
  __hip_bfloat16* w2t = (__hip_bfloat16*)(ws + (size_t)15 * 1048576 + 256 * 1024);  // 12 KB
  // staged (12.8 MB) aliases h0s region: dead before gemm1 writes h0s
  unsigned int* staged = (unsigned int*)(ws + (size_t)16 * 1048576);
  __hip_bfloat16* h0s = (__hip_bfloat16*)(ws + (size_t)16 * 1048576);  // 25.6 MB -> ends 41.6
  __hip_bfloat16* h   = (__hip_bfloat16*)(ws + (size_t)42 * 1048576);  // 25.6 MB -> ends 67.6
  float* h1s          = (float*)(ws + (size_t)16 * 1048576);           // alias h0s (dead after agg1)

  (void)hipMemsetAsync(bcur, 0, (size_t)NB_BKT * 4, stream);

  bin_scatter<<<NWG_BIN, 256, 0, stream>>>(ei, bcur, staged);
  build_bucket<<<NB_BKT, 256, 0, stream>>>(staged, bcur, deg_i, dinv, row_start, adj);

  tr_w<<<(FEAT * HID + NPAD * HID + 255) / 256, 256, 0, stream>>>(W1, W2, w1t, w2t);

  gemm1_kernel<<<(NODES + 63) / 64, 256, 0, stream>>>(x, w1t, dinv, h0s);
  agg1_fused<<<(NODES + 3) / 4, 256, 0, stream>>>(row_start, deg_i, adj, dinv, b1, h0s, h);
  gemm2_kernel<<<(NODES / 16 + 3) / 4, 256, 0, stream>>>(h, w2t, dinv, h1s);
  agg2_fused<<<(NODES + 3) / 4, 256, 0, stream>>>(row_start, deg_i, adj, dinv, b2, h1s, out);
}

// Round 4
// 582.307 us; speedup vs baseline: 1.0029x; 1.0029x over previous
//
#include <hip/hip_runtime.h>
#include <hip/hip_bf16.h>

#define NODES 100000
#define EDGES 1600000
#define FEAT 512
#define HID 128
#define NCLS 40
#define NPAD 48                      // NCLS padded to 3 MFMA n-tiles

// ---- bucketed CSR build params ----
#define NPB 128                          // nodes per bucket (dst >> 7)
#define NB_BKT ((NODES + NPB - 1) / NPB) // 782 buckets
#define CAP 4096                         // slots per bucket (expected 2048, sigma 45)
#define CHUNK 4096                       // edges per workgroup in binning
#define NWG_BIN ((EDGES + CHUNK - 1) / CHUNK)  // 391

typedef __bf16 bf16x8 __attribute__((ext_vector_type(8)));
typedef float f32x4 __attribute__((ext_vector_type(4)));

static __device__ inline __bf16 cvt_bf16(float f) {
  union { __hip_bfloat16 h; __bf16 b; } u;
  u.h = __float2bfloat16(f);
  return u.b;
}

static __device__ inline __hip_bfloat162 pack_bf162(float a, float b) {
  __hip_bfloat162 r;
  r.x = __float2bfloat16(a);
  r.y = __float2bfloat16(b);
  return r;
}

// ---------------- CSR build, bucketed, fixed-capacity ----------------
__global__ __launch_bounds__(256) void bin_scatter(const int* __restrict__ ei,
                                                   int* __restrict__ bcur,
                                                   unsigned int* __restrict__ staged) {
  __shared__ int h[NB_BKT];
  int tid = threadIdx.x;
  for (int i = tid; i < NB_BKT; i += 256) h[i] = 0;
  __syncthreads();
  int base = blockIdx.x * CHUNK;
#pragma unroll
  for (int rep = 0; rep < CHUNK / 1024; rep++) {
    int e = base + rep * 1024 + (tid << 2);
    if (e < EDGES) {  // EDGES % 4 == 0, so full int4 is in-bounds
      int4 d = *(const int4*)(ei + EDGES + e);
      atomicAdd(&h[d.x >> 7], 1);
      atomicAdd(&h[d.y >> 7], 1);
      atomicAdd(&h[d.z >> 7], 1);
      atomicAdd(&h[d.w >> 7], 1);
    }
  }
  __syncthreads();
  for (int i = tid; i < NB_BKT; i += 256) {
    int c = h[i];
    h[i] = c ? atomicAdd(&bcur[i], c) : 0;
  }
  __syncthreads();
#pragma unroll
  for (int rep = 0; rep < CHUNK / 1024; rep++) {
    int e = base + rep * 1024 + (tid << 2);
    if (e < EDGES) {
      int4 s = *(const int4*)(ei + e);
      int4 d = *(const int4*)(ei + EDGES + e);
      int b0 = d.x >> 7;
      int p0 = atomicAdd(&h[b0], 1);
      staged[b0 * CAP + p0] = ((unsigned)s.x << 7) | ((unsigned)d.x & 127u);
      int b1 = d.y >> 7;
      int p1 = atomicAdd(&h[b1], 1);
      staged[b1 * CAP + p1] = ((unsigned)s.y << 7) | ((unsigned)d.y & 127u);
      int b2 = d.z >> 7;
      int p2 = atomicAdd(&h[b2], 1);
      staged[b2 * CAP + p2] = ((unsigned)s.z << 7) | ((unsigned)d.z & 127u);
      int b3 = d.w >> 7;
      int p3 = atomicAdd(&h[b3], 1);
      staged[b3 * CAP + p3] = ((unsigned)s.w << 7) | ((unsigned)d.w & 127u);
    }
  }
}

__global__ __launch_bounds__(256) void build_bucket(const unsigned int* __restrict__ staged,
                                                    const int* __restrict__ bcur,
                                                    int* __restrict__ deg,
                                                    float* __restrict__ dinv,
                                                    int* __restrict__ row_start,
                                                    int* __restrict__ adj) {
  __shared__ int hist[NPB];
  __shared__ int sc[NPB];
  __shared__ int cur[NPB];
  int tid = threadIdx.x;
  int b = blockIdx.x;
  int n0 = b * NPB;
  int s = b * CAP;
  int cnt = bcur[b];
  if (tid < NPB) hist[tid] = 0;
  __syncthreads();
  for (int i = tid; i < cnt; i += 256) {
    unsigned int v = staged[s + i];
    atomicAdd(&hist[v & 127u], 1);
  }
  __syncthreads();
  int pad = 0;
  if (tid < NPB) {
    pad = (hist[tid] + 3) & ~3;  // 16B-aligned rows for int4 adj loads
    sc[tid] = pad;
  }
  __syncthreads();
#pragma unroll
  for (int off = 1; off < NPB; off <<= 1) {
    int t = 0;
    if (tid < NPB && tid >= off) t = sc[tid - off];
    __syncthreads();
    if (tid < NPB && tid >= off) sc[tid] += t;
    __syncthreads();
  }
  if (tid < NPB) {
    int node = n0 + tid;
    int rs = s + sc[tid] - pad;   // sum of pads <= cnt + 3*128 < CAP
    cur[tid] = rs;
    if (node < NODES) {
      row_start[node] = rs;
      deg[node] = hist[tid];
      dinv[node] = rsqrtf((float)hist[tid] + 1.0f);  // +1 = self loop
    }
  }
  __syncthreads();
  for (int i = tid; i < cnt; i += 256) {
    unsigned int v = staged[s + i];
    int pos = atomicAdd(&cur[v & 127u], 1);
    adj[pos] = (int)(v >> 7);
  }
}

// ---------------- weight transposes (f32 -> bf16), merged ----------------
__global__ void tr_w(const float* __restrict__ w1, const float* __restrict__ w2,
                     __hip_bfloat16* __restrict__ w1t, __hip_bfloat16* __restrict__ w2t) {
  int idx = blockIdx.x * blockDim.x + threadIdx.x;
  if (idx < FEAT * HID) {
    int k = idx / HID, n = idx % HID;
    w1t[n * FEAT + k] = __float2bfloat16(w1[idx]);
  } else {
    int j = idx - FEAT * HID;
    if (j < NPAD * HID) {
      int n = j / HID, k = j % HID;
      w2t[n * HID + k] = (n < NCLS) ? __float2bfloat16(w2[k * NCLS + n]) : __float2bfloat16(0.0f);
    }
  }
}

// ---------------- GEMM1 v4: split-K across waves, B in registers ----------------
// Block = 16 rows (grid 6250 exact). Wave w owns K range [w*128, w*128+128).
// B-frags (8n x 4ks = 128 VGPR) preloaded once from L2-resident w1t; all 4 A
// k-steps issued up-front (HBM, 40 outstanding loads/lane); k-loop is pure
// register cvt+MFMA. Partials summed via padded LDS, scaled by dinv, stored bf16.
__global__ __launch_bounds__(256, 2) void gemm1_kernel(const float* __restrict__ x,
                                                       const __hip_bfloat16* __restrict__ w1t,
                                                       const float* __restrict__ dinv,
                                                       __hip_bfloat16* __restrict__ h0s) {
  __shared__ float red[4][16][132];  // 33 KB, +4 pad: ~2-way banks on write
  int tid = threadIdx.x, wave = tid >> 6, lane = tid & 63;
  int r = lane & 15, quad = lane >> 4;
  int m0 = blockIdx.x * 16;
  int kb = wave * 128;

  // A: issue all 4 k-steps (independent HBM loads)
  const float* ap = x + (size_t)(m0 + r) * FEAT + kb + quad * 8;
  f32x4 a0[4], a1[4];
#pragma unroll
  for (int ks = 0; ks < 4; ks++) {
    a0[ks] = *(const f32x4*)(ap + ks * 32);
    a1[ks] = *(const f32x4*)(ap + ks * 32 + 4);
  }
  // B: preload 8n x 4ks fragments (L2-resident w1t)
  const __hip_bfloat16* bp = w1t + (size_t)r * FEAT + kb + quad * 8;
  bf16x8 bfr[8][4];
#pragma unroll
  for (int n = 0; n < 8; n++)
#pragma unroll
    for (int ks = 0; ks < 4; ks++)
      bfr[n][ks] = *(const bf16x8*)(bp + (size_t)n * 16 * FEAT + ks * 32);

  f32x4 acc[8];
#pragma unroll
  for (int n = 0; n < 8; n++) acc[n] = (f32x4){0.f, 0.f, 0.f, 0.f};

#pragma unroll
  for (int ks = 0; ks < 4; ks++) {
    bf16x8 af;
    af[0] = cvt_bf16(a0[ks][0]); af[1] = cvt_bf16(a0[ks][1]);
    af[2] = cvt_bf16(a0[ks][2]); af[3] = cvt_bf16(a0[ks][3]);
    af[4] = cvt_bf16(a1[ks][0]); af[5] = cvt_bf16(a1[ks][1]);
    af[6] = cvt_bf16(a1[ks][2]); af[7] = cvt_bf16(a1[ks][3]);
#pragma unroll
    for (int n = 0; n < 8; n++)
      acc[n] = __builtin_amdgcn_mfma_f32_16x16x32_bf16(af, bfr[n][ks], acc[n], 0, 0, 0);
  }

  // cross-wave K reduction through LDS
#pragma unroll
  for (int n = 0; n < 8; n++)
#pragma unroll
    for (int rr = 0; rr < 4; rr++)
      red[wave][quad * 4 + rr][n * 16 + r] = acc[n][rr];
  __syncthreads();

  // final sum + dinv scale + bf16 store: thread t -> row = t&15, cols (t>>4)*8..+7
  int row = tid & 15, c0 = (tid >> 4) * 8;
  f32x4 s0 = (f32x4){0.f, 0.f, 0.f, 0.f}, s1 = s0;
#pragma unroll
  for (int w = 0; w < 4; w++) {
    s0 += *(const f32x4*)(&red[w][row][c0]);
    s1 += *(const f32x4*)(&red[w][row][c0 + 4]);
  }
  float dv = dinv[m0 + row];
  bf16x8 ob;
  ob[0] = cvt_bf16(s0[0] * dv); ob[1] = cvt_bf16(s0[1] * dv);
  ob[2] = cvt_bf16(s0[2] * dv); ob[3] = cvt_bf16(s0[3] * dv);
  ob[4] = cvt_bf16(s1[0] * dv); ob[5] = cvt_bf16(s1[1] * dv);
  ob[6] = cvt_bf16(s1[2] * dv); ob[7] = cvt_bf16(s1[3] * dv);
  *(bf16x8*)(h0s + (size_t)(m0 + row) * HID + c0) = ob;
}

// ---------------- fused agg1 + epilogue1: h = relu(di * sum(h0s) + b1) ----------------
__global__ __launch_bounds__(256) void agg1_fused(
    const int* __restrict__ row_start, const int* __restrict__ deg,
    const int* __restrict__ adj, const float* __restrict__ dinv,
    const float* __restrict__ b1, const __hip_bfloat16* __restrict__ h0s,
    __hip_bfloat16* __restrict__ h) {
  int wave = threadIdx.x >> 6, lane = threadIdx.x & 63;
  int node = blockIdx.x * 4 + wave;
  if (node >= NODES) return;
  float di = dinv[node];
  float2 f = __bfloat1622float2(((const __hip_bfloat162*)(h0s + (size_t)node * HID))[lane]);
  float ax = f.x, ay = f.y;  // self loop: h0s[node] already carries dinv[node]
  int start = row_start[node], end = start + deg[node];
  int p = start;
  for (; p + 16 <= end; p += 16) {  // row_start is 16B-aligned
    int4 a0 = *(const int4*)(adj + p);
    int4 a1 = *(const int4*)(adj + p + 4);
    int4 a2 = *(const int4*)(adj + p + 8);
    int4 a3 = *(const int4*)(adj + p + 12);
    int s[16] = {a0.x, a0.y, a0.z, a0.w, a1.x, a1.y, a1.z, a1.w,
                 a2.x, a2.y, a2.z, a2.w, a3.x, a3.y, a3.z, a3.w};
    float2 v[16];
#pragma unroll
    for (int j = 0; j < 16; j++)
      v[j] = __bfloat1622float2(((const __hip_bfloat162*)(h0s + (size_t)s[j] * HID))[lane]);
#pragma unroll
    for (int j = 0; j < 16; j++) { ax += v[j].x; ay += v[j].y; }
  }
  if (p + 8 <= end) {
    int4 a0 = *(const int4*)(adj + p);
    int4 a1 = *(const int4*)(adj + p + 4);
    int s[8] = {a0.x, a0.y, a0.z, a0.w, a1.x, a1.y, a1.z, a1.w};
    float2 v[8];
#pragma unroll
    for (int j = 0; j < 8; j++)
      v[j] = __bfloat1622float2(((const __hip_bfloat162*)(h0s + (size_t)s[j] * HID))[lane]);
#pragma unroll
    for (int j = 0; j < 8; j++) { ax += v[j].x; ay += v[j].y; }
    p += 8;
  }
  for (; p < end; ++p) {
    int s = adj[p];
    float2 v = __bfloat1622float2(((const __hip_bfloat162*)(h0s + (size_t)s * HID))[lane]);
    ax += v.x;
    ay += v.y;
  }
  float2 b = ((const float2*)b1)[lane];
  ax = fmaxf(ax * di + b.x, 0.0f);
  ay = fmaxf(ay * di + b.y, 0.0f);
  ((__hip_bfloat162*)(h + (size_t)node * HID))[lane] = pack_bf162(ax, ay);
}

// ---------------- GEMM2: h1s[N,40] = (h[N,128] @ W2) * dinv[row] ----------------
__global__ __launch_bounds__(256) void gemm2_kernel(const __hip_bfloat16* __restrict__ h,
                                                    const __hip_bfloat16* __restrict__ w2t,
                                                    const float* __restrict__ dinv,
                                                    float* __restrict__ h1s) {
  int wave = threadIdx.x >> 6;
  int lane = threadIdx.x & 63;
  int m0 = (blockIdx.x * 4 + wave) * 16;
  if (m0 >= NODES) return;
  int r = lane & 15, quad = lane >> 4;
  const bf16x8* arow = (const bf16x8*)(h + (size_t)(m0 + r) * HID + quad * 8);
  f32x4 acc[3];
#pragma unroll
  for (int n = 0; n < 3; n++) acc[n] = (f32x4){0.f, 0.f, 0.f, 0.f};
#pragma unroll
  for (int k0 = 0; k0 < HID; k0 += 32) {
    bf16x8 a = arow[k0 / 8];
#pragma unroll
    for (int n = 0; n < 3; n++) {
      const bf16x8* brow = (const bf16x8*)(w2t + (size_t)(n * 16 + r) * HID + k0 + quad * 8);
      acc[n] = __builtin_amdgcn_mfma_f32_16x16x32_bf16(a, *brow, acc[n], 0, 0, 0);
    }
  }
  f32x4 dv = *(const f32x4*)(dinv + m0 + quad * 4);
#pragma unroll
  for (int n = 0; n < 3; n++)
#pragma unroll
    for (int rr = 0; rr < 4; rr++) {
      int col = n * 16 + r;
      if (col < NCLS)
        h1s[(size_t)(m0 + quad * 4 + rr) * NCLS + col] = acc[n][rr] * dv[rr];
    }
}

// ---------------- fused agg2 + bias + self loop + log_softmax ----------------
__global__ __launch_bounds__(256) void agg2_fused(
    const int* __restrict__ row_start, const int* __restrict__ deg,
    const int* __restrict__ adj, const float* __restrict__ dinv,
    const float* __restrict__ b2, const float* __restrict__ h1s,
    float* __restrict__ out) {
  int wave = threadIdx.x >> 6, lane = threadIdx.x & 63;
  int node = blockIdx.x * 4 + wave;
  if (node >= NODES) return;
  float di = dinv[node];
  bool act = lane < NCLS;
  float acc = act ? h1s[(size_t)node * NCLS + lane] : 0.0f;  // self loop pre-scaled
  int start = row_start[node], end = start + deg[node];
  int p = start;
  for (; p + 8 <= end; p += 8) {
    int4 a0 = *(const int4*)(adj + p);
    int4 a1 = *(const int4*)(adj + p + 4);
    int s[8] = {a0.x, a0.y, a0.z, a0.w, a1.x, a1.y, a1.z, a1.w};
    if (act) {
      float v[8];
#pragma unroll
      for (int j = 0; j < 8; j++) v[j] = h1s[(size_t)s[j] * NCLS + lane];
#pragma unroll
      for (int j = 0; j < 8; j++) acc += v[j];
    }
  }
  for (; p < end; ++p) {
    int s = adj[p];
    if (act) acc += h1s[(size_t)s * NCLS + lane];
  }
  float v = act ? acc * di + b2[lane] : -1e30f;
  float m = v;
#pragma unroll
  for (int o = 32; o > 0; o >>= 1) m = fmaxf(m, __shfl_xor(m, o));
  float ex = act ? expf(v - m) : 0.0f;
  float ssum = ex;
#pragma unroll
  for (int o = 32; o > 0; o >>= 1) ssum += __shfl_xor(ssum, o);
  if (act) out[(size_t)node * NCLS + lane] = v - m - logf(ssum);
}

extern "C" void kernel_launch(void* const* d_in, const int* in_sizes, int n_in,
                              void* d_out, int out_size, void* d_ws, size_t ws_size,
                              hipStream_t stream) {
  const float* x  = (const float*)d_in[0];
  const int* ei   = (const int*)d_in[1];
  const float* W1 = (const float*)d_in[2];
  const float* b1 = (const float*)d_in[3];
  const float* W2 = (const float*)d_in[4];
  const float* b2 = (const float*)d_in[5];
  float* out = (float*)d_out;

  char* ws = (char*)d_ws;
  int* deg_i          = (int*)(ws + 0);                    // 400 KB
  float* dinv         = (float*)(ws + (size_t)512 * 1024); // 400 KB
  int* row_start      = (int*)(ws + (size_t)1024 * 1024);  // 400 KB
  int* bcur           = (int*)(ws + (size_t)1536 * 1024);  // ~3.1 KB
  int* adj            = (int*)(ws + (size_t)2 * 1048576);  // 12.8 MB -> ends ~14.8 MB
  __hip_bfloat16* w1t = (__hip_bfloat16*)(ws + (size_t)15 * 1048576);  // 128 KB
  __hip_bfloat16* w2t = (__hip_bfloat16*)(ws + (size_t)15 * 1048576 + 256 * 1024);  // 12 KB
  // staged (12.8 MB) aliases h0s region: dead before gemm1 writes h0s
  unsigned int* staged = (unsigned int*)(ws + (size_t)16 * 1048576);
  __hip_bfloat16* h0s = (__hip_bfloat16*)(ws + (size_t)16 * 1048576);  // 25.6 MB -> ends 41.6
  __hip_bfloat16* h   = (__hip_bfloat16*)(ws + (size_t)42 * 1048576);  // 25.6 MB -> ends 67.6
  float* h1s          = (float*)(ws + (size_t)16 * 1048576);           // alias h0s (dead after agg1)

  (void)hipMemsetAsync(bcur, 0, (size_t)NB_BKT * 4, stream);

  bin_scatter<<<NWG_BIN, 256, 0, stream>>>(ei, bcur, staged);
  build_bucket<<<NB_BKT, 256, 0, stream>>>(staged, bcur, deg_i, dinv, row_start, adj);

  tr_w<<<(FEAT * HID + NPAD * HID + 255) / 256, 256, 0, stream>>>(W1, W2, w1t, w2t);

  gemm1_kernel<<<NODES / 16, 256, 0, stream>>>(x, w1t, dinv, h0s);
  agg1_fused<<<(NODES + 3) / 4, 256, 0, stream>>>(row_start, deg_i, adj, dinv, b1, h0s, h);
  gemm2_kernel<<<(NODES / 16 + 3) / 4, 256, 0, stream>>>(h, w2t, dinv, h1s);
  agg2_fused<<<(NODES + 3) / 4, 256, 0, stream>>>(row_start, deg_i, adj, dinv, b2, h1s, out);
}

// Round 5
// 530.406 us; speedup vs baseline: 1.1010x; 1.0979x over previous
//
#include <hip/hip_runtime.h>
#include <hip/hip_bf16.h>

#define NODES 100000
#define EDGES 1600000
#define FEAT 512
#define HID 128
#define NCLS 40
#define NPAD 48                      // NCLS padded to 3 MFMA n-tiles / aligned h1s rows

// ---- bucketed CSR build params ----
#define NPB 128                          // nodes per bucket (dst >> 7)
#define NB_BKT ((NODES + NPB - 1) / NPB) // 782 buckets
#define CAP 4096                         // slots per bucket (expected 2048, sigma 45)
#define CHUNK 4096                       // edges per workgroup in binning
#define NWG_BIN ((EDGES + CHUNK - 1) / CHUNK)  // 391
#define NWG_TRW ((FEAT * HID + NPAD * HID + 255) / 256)  // 257

typedef __bf16 bf16x8 __attribute__((ext_vector_type(8)));
typedef float f32x4 __attribute__((ext_vector_type(4)));

static __device__ inline __bf16 cvt_bf16(float f) {
  union { __hip_bfloat16 h; __bf16 b; } u;
  u.h = __float2bfloat16(f);
  return u.b;
}

static __device__ inline __hip_bfloat162 pack_bf162(float a, float b) {
  __hip_bfloat162 r;
  r.x = __float2bfloat16(a);
  r.y = __float2bfloat16(b);
  return r;
}

// ---------------- CSR build (bucketed, fixed-capacity) + weight transpose ----------------
// blocks [0, NWG_BIN): edge binning; blocks [NWG_BIN, +NWG_TRW): f32->bf16 weight transpose
__global__ __launch_bounds__(256) void bin_scatter_trw(const int* __restrict__ ei,
                                                       int* __restrict__ bcur,
                                                       unsigned int* __restrict__ staged,
                                                       const float* __restrict__ w1,
                                                       const float* __restrict__ w2,
                                                       __hip_bfloat16* __restrict__ w1t,
                                                       __hip_bfloat16* __restrict__ w2t) {
  __shared__ int h[NB_BKT];
  int tid = threadIdx.x;
  if (blockIdx.x >= NWG_BIN) {
    int idx = (blockIdx.x - NWG_BIN) * 256 + tid;
    if (idx < FEAT * HID) {
      int k = idx / HID, n = idx % HID;
      w1t[n * FEAT + k] = __float2bfloat16(w1[idx]);
    } else {
      int j = idx - FEAT * HID;
      if (j < NPAD * HID) {
        int n = j / HID, k = j % HID;
        w2t[n * HID + k] = (n < NCLS) ? __float2bfloat16(w2[k * NCLS + n]) : __float2bfloat16(0.0f);
      }
    }
    return;
  }
  for (int i = tid; i < NB_BKT; i += 256) h[i] = 0;
  __syncthreads();
  int base = blockIdx.x * CHUNK;
#pragma unroll
  for (int rep = 0; rep < CHUNK / 1024; rep++) {
    int e = base + rep * 1024 + (tid << 2);
    if (e < EDGES) {  // EDGES % 4 == 0, so full int4 is in-bounds
      int4 d = *(const int4*)(ei + EDGES + e);
      atomicAdd(&h[d.x >> 7], 1);
      atomicAdd(&h[d.y >> 7], 1);
      atomicAdd(&h[d.z >> 7], 1);
      atomicAdd(&h[d.w >> 7], 1);
    }
  }
  __syncthreads();
  for (int i = tid; i < NB_BKT; i += 256) {
    int c = h[i];
    h[i] = c ? atomicAdd(&bcur[i], c) : 0;
  }
  __syncthreads();
#pragma unroll
  for (int rep = 0; rep < CHUNK / 1024; rep++) {
    int e = base + rep * 1024 + (tid << 2);
    if (e < EDGES) {
      int4 s = *(const int4*)(ei + e);
      int4 d = *(const int4*)(ei + EDGES + e);
      int b0 = d.x >> 7;
      int p0 = atomicAdd(&h[b0], 1);
      staged[b0 * CAP + p0] = ((unsigned)s.x << 7) | ((unsigned)d.x & 127u);
      int b1 = d.y >> 7;
      int p1 = atomicAdd(&h[b1], 1);
      staged[b1 * CAP + p1] = ((unsigned)s.y << 7) | ((unsigned)d.y & 127u);
      int b2 = d.z >> 7;
      int p2 = atomicAdd(&h[b2], 1);
      staged[b2 * CAP + p2] = ((unsigned)s.z << 7) | ((unsigned)d.z & 127u);
      int b3 = d.w >> 7;
      int p3 = atomicAdd(&h[b3], 1);
      staged[b3 * CAP + p3] = ((unsigned)s.w << 7) | ((unsigned)d.w & 127u);
    }
  }
}

__global__ __launch_bounds__(256) void build_bucket(const unsigned int* __restrict__ staged,
                                                    const int* __restrict__ bcur,
                                                    int* __restrict__ deg,
                                                    float* __restrict__ dinv,
                                                    int* __restrict__ row_start,
                                                    int* __restrict__ adj) {
  __shared__ int hist[NPB];
  __shared__ int sc[NPB];
  __shared__ int cur[NPB];
  int tid = threadIdx.x;
  int b = blockIdx.x;
  int n0 = b * NPB;
  int s = b * CAP;
  int cnt = bcur[b];
  if (tid < NPB) hist[tid] = 0;
  __syncthreads();
  for (int i = tid; i < cnt; i += 256) {
    unsigned int v = staged[s + i];
    atomicAdd(&hist[v & 127u], 1);
  }
  __syncthreads();
  int pad = 0;
  if (tid < NPB) {
    pad = (hist[tid] + 3) & ~3;  // 16B-aligned rows for int4 adj loads
    sc[tid] = pad;
  }
  __syncthreads();
#pragma unroll
  for (int off = 1; off < NPB; off <<= 1) {
    int t = 0;
    if (tid < NPB && tid >= off) t = sc[tid - off];
    __syncthreads();
    if (tid < NPB && tid >= off) sc[tid] += t;
    __syncthreads();
  }
  if (tid < NPB) {
    int node = n0 + tid;
    int rs = s + sc[tid] - pad;   // sum of pads <= cnt + 3*128 < CAP
    cur[tid] = rs;
    if (node < NODES) {
      row_start[node] = rs;
      deg[node] = hist[tid];
      dinv[node] = rsqrtf((float)hist[tid] + 1.0f);  // +1 = self loop
    }
  }
  __syncthreads();
  for (int i = tid; i < cnt; i += 256) {
    unsigned int v = staged[s + i];
    int pos = atomicAdd(&cur[v & 127u], 1);
    adj[pos] = (int)(v >> 7);
  }
}

// ---------------- GEMM1 v5: async global_load_lds staging, BK=64 ----------------
// A staged as f32 into LDS (32 KB) via global_load_lds w=16: linear LDS dest,
// XOR-pre-swizzled global source (16B chunk c ^ (row&15)); same XOR on the read.
// B staged via global_load_lds directly into MFMA fragment order (16 KB).
// f32->bf16 conversion happens at LDS->register fragment read. 48 KB LDS ->
// 3 blocks/CU; 12 async 16B loads/thread in flight per chunk.
__global__ __launch_bounds__(256) void gemm1_kernel(const float* __restrict__ x,
                                                    const __hip_bfloat16* __restrict__ w1t,
                                                    const float* __restrict__ dinv,
                                                    __hip_bfloat16* __restrict__ h0s) {
  __shared__ float As[128 * 64];   // 32 KB
  __shared__ bf16x8 Bfrag[1024];   // 16 KB: [(n*2+ks)*64 + lane]
  int tid = threadIdx.x;
  int wave = tid >> 6, lane = tid & 63;
  int r = lane & 15, quad = lane >> 4;
  int m_base = blockIdx.x * 128;

  f32x4 acc[2][8];
#pragma unroll
  for (int mt = 0; mt < 2; mt++)
#pragma unroll
    for (int n = 0; n < 8; n++) acc[mt][n] = (f32x4){0.f, 0.f, 0.f, 0.f};

  for (int ch = 0; ch < 8; ch++) {
    int kc = ch * 64;
    __syncthreads();  // previous chunk's LDS reads done
    // stage A: 128 rows x 64 f32 = 2048 16B slots. slot s -> (row=s>>4, chunk=s&15);
    // source chunk pre-swizzled: c ^ (row&15)
#pragma unroll
    for (int rep = 0; rep < 8; rep++) {
      int s = tid + rep * 256;
      int row = s >> 4, c = s & 15;
      int grow = m_base + row;
      if (grow >= NODES) grow = NODES - 1;  // clamp; epilogue masks stores
      const float* src = x + (size_t)grow * FEAT + kc + ((c ^ (row & 15)) << 2);
      __builtin_amdgcn_global_load_lds(
          (const __attribute__((address_space(1))) unsigned int*)src,
          (__attribute__((address_space(3))) unsigned int*)(As + s * 4), 16, 0, 0);
    }
    // stage B into fragment order: slot f -> (n=f>>7, ks=(f>>6)&1, lane=f&63)
#pragma unroll
    for (int rep = 0; rep < 4; rep++) {
      int f = tid + rep * 256;
      int fl = f & 63, ksl = (f >> 6) & 1, n = f >> 7;
      const __hip_bfloat16* src =
          w1t + (size_t)(n * 16 + (fl & 15)) * FEAT + kc + ksl * 32 + (fl >> 4) * 8;
      __builtin_amdgcn_global_load_lds(
          (const __attribute__((address_space(1))) unsigned int*)src,
          (__attribute__((address_space(3))) unsigned int*)(Bfrag + f), 16, 0, 0);
    }
    __syncthreads();  // compiler drains vmcnt before barrier
    // compute: 2 k-steps x (2 m-tiles x 8 n-tiles)
#pragma unroll
    for (int ks = 0; ks < 2; ks++) {
      bf16x8 bf[8];
#pragma unroll
      for (int n = 0; n < 8; n++) bf[n] = Bfrag[(n * 2 + ks) * 64 + lane];
      int cc = ks * 8 + quad * 2;  // logical 16B chunk of this lane's 32B A slice
#pragma unroll
      for (int mt = 0; mt < 2; mt++) {
        int row = (wave * 2 + mt) * 16 + r;
        f32x4 p0 = *(const f32x4*)(As + row * 64 + ((cc ^ r) << 2));
        f32x4 p1 = *(const f32x4*)(As + row * 64 + (((cc + 1) ^ r) << 2));
        bf16x8 af;
        af[0] = cvt_bf16(p0[0]); af[1] = cvt_bf16(p0[1]);
        af[2] = cvt_bf16(p0[2]); af[3] = cvt_bf16(p0[3]);
        af[4] = cvt_bf16(p1[0]); af[5] = cvt_bf16(p1[1]);
        af[6] = cvt_bf16(p1[2]); af[7] = cvt_bf16(p1[3]);
#pragma unroll
        for (int n = 0; n < 8; n++)
          acc[mt][n] = __builtin_amdgcn_mfma_f32_16x16x32_bf16(af, bf[n], acc[mt][n], 0, 0, 0);
      }
    }
  }
#pragma unroll
  for (int mt = 0; mt < 2; mt++) {
    int mrow = m_base + (wave * 2 + mt) * 16 + quad * 4;
    f32x4 dv = *(const f32x4*)(dinv + mrow);  // mrow%4==0; OOB rows read ws slack, unused
#pragma unroll
    for (int n = 0; n < 8; n++)
#pragma unroll
      for (int rr = 0; rr < 4; rr++) {
        int row = mrow + rr;
        if (row < NODES)
          h0s[(size_t)row * HID + n * 16 + r] = __float2bfloat16(acc[mt][n][rr] * dv[rr]);
      }
  }
}

// ---------------- fused agg1 + epilogue1: h = relu(di * sum(h0s) + b1) ----------------
__global__ __launch_bounds__(256) void agg1_fused(
    const int* __restrict__ row_start, const int* __restrict__ deg,
    const int* __restrict__ adj, const float* __restrict__ dinv,
    const float* __restrict__ b1, const __hip_bfloat16* __restrict__ h0s,
    __hip_bfloat16* __restrict__ h) {
  int wave = threadIdx.x >> 6, lane = threadIdx.x & 63;
  int node = blockIdx.x * 4 + wave;
  if (node >= NODES) return;
  float di = dinv[node];
  float2 f = __bfloat1622float2(((const __hip_bfloat162*)(h0s + (size_t)node * HID))[lane]);
  float ax = f.x, ay = f.y;  // self loop: h0s[node] already carries dinv[node]
  int start = row_start[node], end = start + deg[node];
  int p = start;
  for (; p + 16 <= end; p += 16) {  // row_start is 16B-aligned
    int4 a0 = *(const int4*)(adj + p);
    int4 a1 = *(const int4*)(adj + p + 4);
    int4 a2 = *(const int4*)(adj + p + 8);
    int4 a3 = *(const int4*)(adj + p + 12);
    int s[16] = {a0.x, a0.y, a0.z, a0.w, a1.x, a1.y, a1.z, a1.w,
                 a2.x, a2.y, a2.z, a2.w, a3.x, a3.y, a3.z, a3.w};
    float2 v[16];
#pragma unroll
    for (int j = 0; j < 16; j++)
      v[j] = __bfloat1622float2(((const __hip_bfloat162*)(h0s + (size_t)s[j] * HID))[lane]);
#pragma unroll
    for (int j = 0; j < 16; j++) { ax += v[j].x; ay += v[j].y; }
  }
  if (p + 8 <= end) {
    int4 a0 = *(const int4*)(adj + p);
    int4 a1 = *(const int4*)(adj + p + 4);
    int s[8] = {a0.x, a0.y, a0.z, a0.w, a1.x, a1.y, a1.z, a1.w};
    float2 v[8];
#pragma unroll
    for (int j = 0; j < 8; j++)
      v[j] = __bfloat1622float2(((const __hip_bfloat162*)(h0s + (size_t)s[j] * HID))[lane]);
#pragma unroll
    for (int j = 0; j < 8; j++) { ax += v[j].x; ay += v[j].y; }
    p += 8;
  }
  for (; p < end; ++p) {
    int s = adj[p];
    float2 v = __bfloat1622float2(((const __hip_bfloat162*)(h0s + (size_t)s * HID))[lane]);
    ax += v.x;
    ay += v.y;
  }
  float2 b = ((const float2*)b1)[lane];
  ax = fmaxf(ax * di + b.x, 0.0f);
  ay = fmaxf(ay * di + b.y, 0.0f);
  ((__hip_bfloat162*)(h + (size_t)node * HID))[lane] = pack_bf162(ax, ay);
}

// ---------------- GEMM2: h1s[N,48] = (h[N,128] @ W2pad) * dinv[row] ----------------
// rows padded to 48 f32 (192 B, 64B-aligned); cols 40-47 are exact zeros (w2t pad)
__global__ __launch_bounds__(256) void gemm2_kernel(const __hip_bfloat16* __restrict__ h,
                                                    const __hip_bfloat16* __restrict__ w2t,
                                                    const float* __restrict__ dinv,
                                                    float* __restrict__ h1s) {
  int wave = threadIdx.x >> 6;
  int lane = threadIdx.x & 63;
  int m0 = (blockIdx.x * 4 + wave) * 16;
  if (m0 >= NODES) return;
  int r = lane & 15, quad = lane >> 4;
  const bf16x8* arow = (const bf16x8*)(h + (size_t)(m0 + r) * HID + quad * 8);
  f32x4 acc[3];
#pragma unroll
  for (int n = 0; n < 3; n++) acc[n] = (f32x4){0.f, 0.f, 0.f, 0.f};
#pragma unroll
  for (int k0 = 0; k0 < HID; k0 += 32) {
    bf16x8 a = arow[k0 / 8];
#pragma unroll
    for (int n = 0; n < 3; n++) {
      const bf16x8* brow = (const bf16x8*)(w2t + (size_t)(n * 16 + r) * HID + k0 + quad * 8);
      acc[n] = __builtin_amdgcn_mfma_f32_16x16x32_bf16(a, *brow, acc[n], 0, 0, 0);
    }
  }
  f32x4 dv = *(const f32x4*)(dinv + m0 + quad * 4);
#pragma unroll
  for (int n = 0; n < 3; n++)
#pragma unroll
    for (int rr = 0; rr < 4; rr++)
      h1s[(size_t)(m0 + quad * 4 + rr) * NPAD + n * 16 + r] = acc[n][rr] * dv[rr];
}

// ---------------- fused agg2 + bias + self loop + log_softmax ----------------
__global__ __launch_bounds__(256) void agg2_fused(
    const int* __restrict__ row_start, const int* __restrict__ deg,
    const int* __restrict__ adj, const float* __restrict__ dinv,
    const float* __restrict__ b2, const float* __restrict__ h1s,
    float* __restrict__ out) {
  int wave = threadIdx.x >> 6, lane = threadIdx.x & 63;
  int node = blockIdx.x * 4 + wave;
  if (node >= NODES) return;
  float di = dinv[node];
  bool actg = lane < NPAD;  // 48 lanes gather the aligned 192B row (pad cols are 0)
  float acc = actg ? h1s[(size_t)node * NPAD + lane] : 0.0f;  // self loop pre-scaled
  int start = row_start[node], end = start + deg[node];
  int p = start;
  for (; p + 8 <= end; p += 8) {
    int4 a0 = *(const int4*)(adj + p);
    int4 a1 = *(const int4*)(adj + p + 4);
    int s[8] = {a0.x, a0.y, a0.z, a0.w, a1.x, a1.y, a1.z, a1.w};
    if (actg) {
      float v[8];
#pragma unroll
      for (int j = 0; j < 8; j++) v[j] = h1s[(size_t)s[j] * NPAD + lane];
#pragma unroll
      for (int j = 0; j < 8; j++) acc += v[j];
    }
  }
  for (; p < end; ++p) {
    int s = adj[p];
    if (actg) acc += h1s[(size_t)s * NPAD + lane];
  }
  bool act = lane < NCLS;
  float v = act ? acc * di + b2[lane] : -1e30f;
  float m = v;
#pragma unroll
  for (int o = 32; o > 0; o >>= 1) m = fmaxf(m, __shfl_xor(m, o));
  float ex = act ? expf(v - m) : 0.0f;
  float ssum = ex;
#pragma unroll
  for (int o = 32; o > 0; o >>= 1) ssum += __shfl_xor(ssum, o);
  if (act) out[(size_t)node * NCLS + lane] = v - m - logf(ssum);
}

extern "C" void kernel_launch(void* const* d_in, const int* in_sizes, int n_in,
                              void* d_out, int out_size, void* d_ws, size_t ws_size,
                              hipStream_t stream) {
  const float* x  = (const float*)d_in[0];
  const int* ei   = (const int*)d_in[1];
  const float* W1 = (const float*)d_in[2];
  const float* b1 = (const float*)d_in[3];
  const float* W2 = (const float*)d_in[4];
  const float* b2 = (const float*)d_in[5];
  float* out = (float*)d_out;

  char* ws = (char*)d_ws;
  int* deg_i          = (int*)(ws + 0);                    // 400 KB
  float* dinv         = (float*)(ws + (size_t)512 * 1024); // 400 KB
  int* row_start      = (int*)(ws + (size_t)1024 * 1024);  // 400 KB
  int* bcur           = (int*)(ws + (size_t)1536 * 1024);  // ~3.1 KB
  int* adj            = (int*)(ws + (size_t)2 * 1048576);  // 12.8 MB -> ends ~14.8 MB
  __hip_bfloat16* w1t = (__hip_bfloat16*)(ws + (size_t)15 * 1048576);  // 128 KB
  __hip_bfloat16* w2t = (__hip_bfloat16*)(ws + (size_t)15 * 1048576 + 256 * 1024);  // 12 KB
  // staged (12.8 MB) aliases h0s region: dead before gemm1 writes h0s
  unsigned int* staged = (unsigned int*)(ws + (size_t)16 * 1048576);
  __hip_bfloat16* h0s = (__hip_bfloat16*)(ws + (size_t)16 * 1048576);  // 25.6 MB -> ends 41.6
  __hip_bfloat16* h   = (__hip_bfloat16*)(ws + (size_t)42 * 1048576);  // 25.6 MB -> ends 67.6
  float* h1s          = (float*)(ws + (size_t)16 * 1048576);           // 19.2 MB, alias h0s (dead after agg1)

  (void)hipMemsetAsync(bcur, 0, (size_t)NB_BKT * 4, stream);

  bin_scatter_trw<<<NWG_BIN + NWG_TRW, 256, 0, stream>>>(ei, bcur, staged, W1, W2, w1t, w2t);
  build_bucket<<<NB_BKT, 256, 0, stream>>>(staged, bcur, deg_i, dinv, row_start, adj);

  gemm1_kernel<<<(NODES + 127) / 128, 256, 0, stream>>>(x, w1t, dinv, h0s);
  agg1_fused<<<(NODES + 3) / 4, 256, 0, stream>>>(row_start, deg_i, adj, dinv, b1, h0s, h);
  gemm2_kernel<<<(NODES / 16 + 3) / 4, 256, 0, stream>>>(h, w2t, dinv, h1s);
  agg2_fused<<<(NODES + 3) / 4, 256, 0, stream>>>(row_start, deg_i, adj, dinv, b2, h1s, out);
}

// Round 6
// 517.503 us; speedup vs baseline: 1.1285x; 1.0249x over previous
//
#include <hip/hip_runtime.h>
#include <hip/hip_bf16.h>

#define NODES 100000
#define EDGES 1600000
#define FEAT 512
#define HID 128
#define NCLS 40
#define NPAD 48                      // NCLS padded to 3 MFMA n-tiles / aligned h1s rows

// ---- bucketed CSR build params ----
#define NPB 128                          // nodes per bucket (dst >> 7)
#define NB_BKT ((NODES + NPB - 1) / NPB) // 782 buckets
#define CAP 4096                         // slots per bucket (expected 2046, sigma 45)
#define CHUNK 8192                       // edges per workgroup in binning
#define NWG_BIN ((EDGES + CHUNK - 1) / CHUNK)  // 196
#define NWG_TRW ((FEAT * HID + NPAD * HID + 255) / 256)  // 257

typedef __bf16 bf16x8 __attribute__((ext_vector_type(8)));
typedef float f32x4 __attribute__((ext_vector_type(4)));

static __device__ inline __bf16 cvt_bf16(float f) {
  union { __hip_bfloat16 h; __bf16 b; } u;
  u.h = __float2bfloat16(f);
  return u.b;
}

static __device__ inline __hip_bfloat162 pack_bf162(float a, float b) {
  __hip_bfloat162 r;
  r.x = __float2bfloat16(a);
  r.y = __float2bfloat16(b);
  return r;
}

// ---------------- CSR build (bucketed, fixed-capacity) + weight transpose ----------------
// blocks [0, NWG_BIN): edge binning; blocks [NWG_BIN, +NWG_TRW): f32->bf16 weight transpose
__global__ __launch_bounds__(256) void bin_scatter_trw(const int* __restrict__ ei,
                                                       int* __restrict__ bcur,
                                                       unsigned int* __restrict__ staged,
                                                       const float* __restrict__ w1,
                                                       const float* __restrict__ w2,
                                                       __hip_bfloat16* __restrict__ w1t,
                                                       __hip_bfloat16* __restrict__ w2t) {
  __shared__ int h[NB_BKT];
  int tid = threadIdx.x;
  if (blockIdx.x >= NWG_BIN) {
    int idx = (blockIdx.x - NWG_BIN) * 256 + tid;
    if (idx < FEAT * HID) {
      int k = idx / HID, n = idx % HID;
      w1t[n * FEAT + k] = __float2bfloat16(w1[idx]);
    } else {
      int j = idx - FEAT * HID;
      if (j < NPAD * HID) {
        int n = j / HID, k = j % HID;
        w2t[n * HID + k] = (n < NCLS) ? __float2bfloat16(w2[k * NCLS + n]) : __float2bfloat16(0.0f);
      }
    }
    return;
  }
  for (int i = tid; i < NB_BKT; i += 256) h[i] = 0;
  __syncthreads();
  int base = blockIdx.x * CHUNK;
  // pass A: count this chunk
#pragma unroll
  for (int rep = 0; rep < CHUNK / 1024; rep++) {
    int e = base + rep * 1024 + (tid << 2);
    if (e < EDGES) {  // EDGES % 4 == 0, so full int4 is in-bounds
      int4 d = *(const int4*)(ei + EDGES + e);
      atomicAdd(&h[d.x >> 7], 1);
      atomicAdd(&h[d.y >> 7], 1);
      atomicAdd(&h[d.z >> 7], 1);
      atomicAdd(&h[d.w >> 7], 1);
    }
  }
  __syncthreads();
  // reserve within-bucket ranges; convert h[] into running write cursors
  for (int i = tid; i < NB_BKT; i += 256) {
    int c = h[i];
    h[i] = c ? atomicAdd(&bcur[i], c) : 0;
  }
  __syncthreads();
  // pass B: scatter packed payloads (src<<7 | dst&127) into reserved runs
#pragma unroll
  for (int rep = 0; rep < CHUNK / 1024; rep++) {
    int e = base + rep * 1024 + (tid << 2);
    if (e < EDGES) {
      int4 s = *(const int4*)(ei + e);
      int4 d = *(const int4*)(ei + EDGES + e);
      int b0 = d.x >> 7;
      int p0 = atomicAdd(&h[b0], 1);
      staged[b0 * CAP + p0] = ((unsigned)s.x << 7) | ((unsigned)d.x & 127u);
      int b1 = d.y >> 7;
      int p1 = atomicAdd(&h[b1], 1);
      staged[b1 * CAP + p1] = ((unsigned)s.y << 7) | ((unsigned)d.y & 127u);
      int b2 = d.z >> 7;
      int p2 = atomicAdd(&h[b2], 1);
      staged[b2 * CAP + p2] = ((unsigned)s.z << 7) | ((unsigned)d.z & 127u);
      int b3 = d.w >> 7;
      int p3 = atomicAdd(&h[b3], 1);
      staged[b3 * CAP + p3] = ((unsigned)s.w << 7) | ((unsigned)d.w & 127u);
    }
  }
}

__global__ __launch_bounds__(256) void build_bucket(const unsigned int* __restrict__ staged,
                                                    const int* __restrict__ bcur,
                                                    int* __restrict__ deg,
                                                    float* __restrict__ dinv,
                                                    int* __restrict__ row_start,
                                                    int* __restrict__ adj) {
  __shared__ int hist[NPB];
  __shared__ int sc[NPB];
  __shared__ int cur[NPB];
  int tid = threadIdx.x;
  int b = blockIdx.x;
  int n0 = b * NPB;
  int s = b * CAP;
  int cnt = bcur[b];
  if (tid < NPB) hist[tid] = 0;
  __syncthreads();
  for (int i = tid; i < cnt; i += 256) {
    unsigned int v = staged[s + i];
    atomicAdd(&hist[v & 127u], 1);
  }
  __syncthreads();
  int pad = 0;
  if (tid < NPB) {
    pad = (hist[tid] + 3) & ~3;  // 16B-aligned rows for int4 adj loads
    sc[tid] = pad;
  }
  __syncthreads();
#pragma unroll
  for (int off = 1; off < NPB; off <<= 1) {
    int t = 0;
    if (tid < NPB && tid >= off) t = sc[tid - off];
    __syncthreads();
    if (tid < NPB && tid >= off) sc[tid] += t;
    __syncthreads();
  }
  if (tid < NPB) {
    int node = n0 + tid;
    int rs = s + sc[tid] - pad;   // sum of pads <= cnt + 3*128 < CAP
    cur[tid] = rs;
    if (node < NODES) {
      row_start[node] = rs;
      deg[node] = hist[tid];
      dinv[node] = rsqrtf((float)hist[tid] + 1.0f);  // +1 = self loop
    }
  }
  __syncthreads();
  for (int i = tid; i < cnt; i += 256) {
    unsigned int v = staged[s + i];
    int pos = atomicAdd(&cur[v & 127u], 1);
    adj[pos] = (int)(v >> 7);
  }
}

// ---------------- GEMM1 v5: async global_load_lds staging, BK=64 ----------------
__global__ __launch_bounds__(256) void gemm1_kernel(const float* __restrict__ x,
                                                    const __hip_bfloat16* __restrict__ w1t,
                                                    const float* __restrict__ dinv,
                                                    __hip_bfloat16* __restrict__ h0s) {
  __shared__ float As[128 * 64];   // 32 KB
  __shared__ bf16x8 Bfrag[1024];   // 16 KB: [(n*2+ks)*64 + lane]
  int tid = threadIdx.x;
  int wave = tid >> 6, lane = tid & 63;
  int r = lane & 15, quad = lane >> 4;
  int m_base = blockIdx.x * 128;

  f32x4 acc[2][8];
#pragma unroll
  for (int mt = 0; mt < 2; mt++)
#pragma unroll
    for (int n = 0; n < 8; n++) acc[mt][n] = (f32x4){0.f, 0.f, 0.f, 0.f};

  for (int ch = 0; ch < 8; ch++) {
    int kc = ch * 64;
    __syncthreads();  // previous chunk's LDS reads done
    // stage A: 128 rows x 64 f32 = 2048 16B slots; source chunk pre-swizzled c^(row&15)
#pragma unroll
    for (int rep = 0; rep < 8; rep++) {
      int s = tid + rep * 256;
      int row = s >> 4, c = s & 15;
      int grow = m_base + row;
      if (grow >= NODES) grow = NODES - 1;  // clamp; epilogue masks stores
      const float* src = x + (size_t)grow * FEAT + kc + ((c ^ (row & 15)) << 2);
      __builtin_amdgcn_global_load_lds(
          (const __attribute__((address_space(1))) unsigned int*)src,
          (__attribute__((address_space(3))) unsigned int*)(As + s * 4), 16, 0, 0);
    }
    // stage B into fragment order: slot f -> (n=f>>7, ks=(f>>6)&1, lane=f&63)
#pragma unroll
    for (int rep = 0; rep < 4; rep++) {
      int f = tid + rep * 256;
      int fl = f & 63, ksl = (f >> 6) & 1, n = f >> 7;
      const __hip_bfloat16* src =
          w1t + (size_t)(n * 16 + (fl & 15)) * FEAT + kc + ksl * 32 + (fl >> 4) * 8;
      __builtin_amdgcn_global_load_lds(
          (const __attribute__((address_space(1))) unsigned int*)src,
          (__attribute__((address_space(3))) unsigned int*)(Bfrag + f), 16, 0, 0);
    }
    __syncthreads();  // compiler drains vmcnt before barrier
#pragma unroll
    for (int ks = 0; ks < 2; ks++) {
      bf16x8 bf[8];
#pragma unroll
      for (int n = 0; n < 8; n++) bf[n] = Bfrag[(n * 2 + ks) * 64 + lane];
      int cc = ks * 8 + quad * 2;  // logical 16B chunk of this lane's 32B A slice
#pragma unroll
      for (int mt = 0; mt < 2; mt++) {
        int row = (wave * 2 + mt) * 16 + r;
        f32x4 p0 = *(const f32x4*)(As + row * 64 + ((cc ^ r) << 2));
        f32x4 p1 = *(const f32x4*)(As + row * 64 + (((cc + 1) ^ r) << 2));
        bf16x8 af;
        af[0] = cvt_bf16(p0[0]); af[1] = cvt_bf16(p0[1]);
        af[2] = cvt_bf16(p0[2]); af[3] = cvt_bf16(p0[3]);
        af[4] = cvt_bf16(p1[0]); af[5] = cvt_bf16(p1[1]);
        af[6] = cvt_bf16(p1[2]); af[7] = cvt_bf16(p1[3]);
#pragma unroll
        for (int n = 0; n < 8; n++)
          acc[mt][n] = __builtin_amdgcn_mfma_f32_16x16x32_bf16(af, bf[n], acc[mt][n], 0, 0, 0);
      }
    }
  }
#pragma unroll
  for (int mt = 0; mt < 2; mt++) {
    int mrow = m_base + (wave * 2 + mt) * 16 + quad * 4;
    f32x4 dv = *(const f32x4*)(dinv + mrow);  // mrow%4==0; OOB rows read ws slack, unused
#pragma unroll
    for (int n = 0; n < 8; n++)
#pragma unroll
      for (int rr = 0; rr < 4; rr++) {
        int row = mrow + rr;
        if (row < NODES)
          h0s[(size_t)row * HID + n * 16 + r] = __float2bfloat16(acc[mt][n][rr] * dv[rr]);
      }
  }
}

// ---------------- fused agg1 + relu + GEMM2: h1s = (relu(agg) @ W2) * dinv ----------------
// block = 16 nodes (grid 6250 exact), 4 waves. Phase 1: wave w aggregates nodes
// w*4..w*4+3 serially, parks relu'd bf16 h-rows in LDS (h never hits global).
// Phase 2: 16x128 @ 128x48 MFMA from LDS; wave n (<3) computes n-tile n.
__global__ __launch_bounds__(256) void agg1g2(
    const int* __restrict__ row_start, const int* __restrict__ deg,
    const int* __restrict__ adj, const float* __restrict__ dinv,
    const float* __restrict__ b1, const __hip_bfloat16* __restrict__ h0s,
    const __hip_bfloat16* __restrict__ w2t, float* __restrict__ h1s) {
  __shared__ __hip_bfloat162 hrow[16][68];  // row stride 272 B (16B-mult, bank-spread)
  int wave = threadIdx.x >> 6, lane = threadIdx.x & 63;
  int nb = blockIdx.x * 16;
  float2 b = ((const float2*)b1)[lane];
#pragma unroll 1
  for (int i = 0; i < 4; i++) {
    int node = nb + wave * 4 + i;  // always < NODES (grid exact)
    float di = dinv[node];
    float2 f = __bfloat1622float2(((const __hip_bfloat162*)(h0s + (size_t)node * HID))[lane]);
    float ax = f.x, ay = f.y;  // self loop: h0s[node] carries dinv[node]
    int start = row_start[node], end = start + deg[node];
    int p = start;
    for (; p + 16 <= end; p += 16) {  // row_start is 16B-aligned
      int4 a0 = *(const int4*)(adj + p);
      int4 a1 = *(const int4*)(adj + p + 4);
      int4 a2 = *(const int4*)(adj + p + 8);
      int4 a3 = *(const int4*)(adj + p + 12);
      int s[16] = {a0.x, a0.y, a0.z, a0.w, a1.x, a1.y, a1.z, a1.w,
                   a2.x, a2.y, a2.z, a2.w, a3.x, a3.y, a3.z, a3.w};
      float2 v[16];
#pragma unroll
      for (int j = 0; j < 16; j++)
        v[j] = __bfloat1622float2(((const __hip_bfloat162*)(h0s + (size_t)s[j] * HID))[lane]);
#pragma unroll
      for (int j = 0; j < 16; j++) { ax += v[j].x; ay += v[j].y; }
    }
    if (p + 8 <= end) {
      int4 a0 = *(const int4*)(adj + p);
      int4 a1 = *(const int4*)(adj + p + 4);
      int s[8] = {a0.x, a0.y, a0.z, a0.w, a1.x, a1.y, a1.z, a1.w};
      float2 v[8];
#pragma unroll
      for (int j = 0; j < 8; j++)
        v[j] = __bfloat1622float2(((const __hip_bfloat162*)(h0s + (size_t)s[j] * HID))[lane]);
#pragma unroll
      for (int j = 0; j < 8; j++) { ax += v[j].x; ay += v[j].y; }
      p += 8;
    }
    for (; p < end; ++p) {
      int s = adj[p];
      float2 v = __bfloat1622float2(((const __hip_bfloat162*)(h0s + (size_t)s * HID))[lane]);
      ax += v.x;
      ay += v.y;
    }
    ax = fmaxf(ax * di + b.x, 0.0f);
    ay = fmaxf(ay * di + b.y, 0.0f);
    hrow[wave * 4 + i][lane] = pack_bf162(ax, ay);  // same bf16 rounding as old h store
  }
  __syncthreads();
  if (wave < 3) {  // n-tile = wave
    int r = lane & 15, quad = lane >> 4;
    f32x4 acc = (f32x4){0.f, 0.f, 0.f, 0.f};
#pragma unroll
    for (int k0 = 0; k0 < HID; k0 += 32) {
      // A-frag: lane (r,quad) holds h[row=r][k0+quad*8 .. +7] = 4 bf162 pairs, 16B aligned
      bf16x8 af = *(const bf16x8*)(&hrow[r][(k0 >> 1) + quad * 4]);
      bf16x8 bf = *(const bf16x8*)(w2t + (size_t)(wave * 16 + r) * HID + k0 + quad * 8);
      acc = __builtin_amdgcn_mfma_f32_16x16x32_bf16(af, bf, acc, 0, 0, 0);
    }
    f32x4 dv = *(const f32x4*)(dinv + nb + quad * 4);
#pragma unroll
    for (int rr = 0; rr < 4; rr++)
      h1s[(size_t)(nb + quad * 4 + rr) * NPAD + wave * 16 + r] = acc[rr] * dv[rr];
  }
}

// ---------------- fused agg2 + bias + self loop + log_softmax ----------------
__global__ __launch_bounds__(256) void agg2_fused(
    const int* __restrict__ row_start, const int* __restrict__ deg,
    const int* __restrict__ adj, const float* __restrict__ dinv,
    const float* __restrict__ b2, const float* __restrict__ h1s,
    float* __restrict__ out) {
  int wave = threadIdx.x >> 6, lane = threadIdx.x & 63;
  int node = blockIdx.x * 4 + wave;
  if (node >= NODES) return;
  float di = dinv[node];
  bool actg = lane < NPAD;  // 48 lanes gather the aligned 192B row (pad cols are 0)
  float acc = actg ? h1s[(size_t)node * NPAD + lane] : 0.0f;  // self loop pre-scaled
  int start = row_start[node], end = start + deg[node];
  int p = start;
  for (; p + 16 <= end; p += 16) {
    int4 a0 = *(const int4*)(adj + p);
    int4 a1 = *(const int4*)(adj + p + 4);
    int4 a2 = *(const int4*)(adj + p + 8);
    int4 a3 = *(const int4*)(adj + p + 12);
    int s[16] = {a0.x, a0.y, a0.z, a0.w, a1.x, a1.y, a1.z, a1.w,
                 a2.x, a2.y, a2.z, a2.w, a3.x, a3.y, a3.z, a3.w};
    if (actg) {
      float v[16];
#pragma unroll
      for (int j = 0; j < 16; j++) v[j] = h1s[(size_t)s[j] * NPAD + lane];
#pragma unroll
      for (int j = 0; j < 16; j++) acc += v[j];
    }
  }
  if (p + 8 <= end) {
    int4 a0 = *(const int4*)(adj + p);
    int4 a1 = *(const int4*)(adj + p + 4);
    int s[8] = {a0.x, a0.y, a0.z, a0.w, a1.x, a1.y, a1.z, a1.w};
    if (actg) {
      float v[8];
#pragma unroll
      for (int j = 0; j < 8; j++) v[j] = h1s[(size_t)s[j] * NPAD + lane];
#pragma unroll
      for (int j = 0; j < 8; j++) acc += v[j];
    }
    p += 8;
  }
  for (; p < end; ++p) {
    int s = adj[p];
    if (actg) acc += h1s[(size_t)s * NPAD + lane];
  }
  bool act = lane < NCLS;
  float v = act ? acc * di + b2[lane] : -1e30f;
  float m = v;
#pragma unroll
  for (int o = 32; o > 0; o >>= 1) m = fmaxf(m, __shfl_xor(m, o));
  float ex = act ? expf(v - m) : 0.0f;
  float ssum = ex;
#pragma unroll
  for (int o = 32; o > 0; o >>= 1) ssum += __shfl_xor(ssum, o);
  if (act) out[(size_t)node * NCLS + lane] = v - m - logf(ssum);
}

extern "C" void kernel_launch(void* const* d_in, const int* in_sizes, int n_in,
                              void* d_out, int out_size, void* d_ws, size_t ws_size,
                              hipStream_t stream) {
  const float* x  = (const float*)d_in[0];
  const int* ei   = (const int*)d_in[1];
  const float* W1 = (const float*)d_in[2];
  const float* b1 = (const float*)d_in[3];
  const float* W2 = (const float*)d_in[4];
  const float* b2 = (const float*)d_in[5];
  float* out = (float*)d_out;

  char* ws = (char*)d_ws;
  int* deg_i          = (int*)(ws + 0);                    // 400 KB
  float* dinv         = (float*)(ws + (size_t)512 * 1024); // 400 KB
  int* row_start      = (int*)(ws + (size_t)1024 * 1024);  // 400 KB
  int* bcur           = (int*)(ws + (size_t)1536 * 1024);  // ~3.1 KB
  int* adj            = (int*)(ws + (size_t)2 * 1048576);  // 12.8 MB -> ends ~14.8 MB
  __hip_bfloat16* w1t = (__hip_bfloat16*)(ws + (size_t)15 * 1048576);  // 128 KB
  __hip_bfloat16* w2t = (__hip_bfloat16*)(ws + (size_t)15 * 1048576 + 256 * 1024);  // 12 KB
  // staged (12.8 MB) aliases h0s region: dead before gemm1 writes h0s
  unsigned int* staged = (unsigned int*)(ws + (size_t)16 * 1048576);
  __hip_bfloat16* h0s = (__hip_bfloat16*)(ws + (size_t)16 * 1048576);  // 25.6 MB -> ends 41.6
  float* h1s          = (float*)(ws + (size_t)42 * 1048576);           // 19.2 MB (must NOT alias h0s:
                                                                       // agg1g2 reads h0s while writing h1s)

  (void)hipMemsetAsync(bcur, 0, (size_t)NB_BKT * 4, stream);

  bin_scatter_trw<<<NWG_BIN + NWG_TRW, 256, 0, stream>>>(ei, bcur, staged, W1, W2, w1t, w2t);
  build_bucket<<<NB_BKT, 256, 0, stream>>>(staged, bcur, deg_i, dinv, row_start, adj);

  gemm1_kernel<<<(NODES + 127) / 128, 256, 0, stream>>>(x, w1t, dinv, h0s);
  agg1g2<<<NODES / 16, 256, 0, stream>>>(row_start, deg_i, adj, dinv, b1, h0s, w2t, h1s);
  agg2_fused<<<(NODES + 3) / 4, 256, 0, stream>>>(row_start, deg_i, adj, dinv, b2, h1s, out);
}